// Round 11
// baseline (179.684 us; speedup 1.0000x reference)
//
#include <hip/hip_runtime.h>
#include <hip/hip_bf16.h>

// SparseMHA, fixed out-degree CSR graph attention. fp32 in/out.
// r10 -> r11: totals decomposition across r8-r10 gives fixed-overhead ~76us,
// attn ~54-56us, qkv_fused ~41us. r10's LDS merge was useless because the
// real qkv limiter is grid size: 391 blocks = 1.53 blocks/CU -- nothing to
// overlap the 9-barrier serial chain with. Now 64-row blocks (wave = 16 rows,
// single A-fragment): 782 blocks = 3.05/CU, LDS 32KB, VGPR ~100.
// attn reverted to r9 verbatim (r10 trims: +1.4us, +3MB FETCH).

typedef unsigned short ushort_t;
typedef unsigned int uint32;
typedef short short8 __attribute__((ext_vector_type(8)));
typedef short short4v __attribute__((ext_vector_type(4)));
typedef float f32x4 __attribute__((ext_vector_type(4)));

#define HID 128
#define DEG 16
#define OSTRIDE_LDS 132   // ushort row stride in LDS repack (bank-conflict-free)

__device__ __forceinline__ float bf2f(ushort_t u) {
  uint32 x = ((uint32)u) << 16;
  return __builtin_bit_cast(float, x);
}
__device__ __forceinline__ ushort_t f2bf(float f) {
  uint32 u = __builtin_bit_cast(uint32, f);
  u += 0x7fffu + ((u >> 16) & 1u);   // RNE
  return (ushort_t)(u >> 16);
}

// Packed split of 2 fp32 -> packed bf16 hi pair + lo pair (RNE, v_cvt_pk path).
__device__ __forceinline__ void split2(float x, float y, uint32& hi, uint32& lo) {
  __hip_bfloat162 h2 = __float22bfloat162_rn(float2{x, y});
  __builtin_memcpy(&hi, &h2, 4);
  float hx = __builtin_bit_cast(float, hi << 16);
  float hy = __builtin_bit_cast(float, hi & 0xffff0000u);
  __hip_bfloat162 l2 = __float22bfloat162_rn(float2{x - hx, y - hy});
  __builtin_memcpy(&lo, &l2, 4);
}

__device__ __forceinline__ void split8v(float4 a, float4 b, short8& hi, short8& lo) {
  uint32* hu = (uint32*)&hi;
  uint32* lu = (uint32*)&lo;
  split2(a.x, a.y, hu[0], lu[0]);
  split2(a.z, a.w, hu[1], lu[1]);
  split2(b.x, b.y, hu[2], lu[2]);
  split2(b.z, b.w, hu[3], lu[3]);
}

__device__ __forceinline__ void split8p(const float* __restrict__ p, short8& hi, short8& lo) {
  float4 a = *(const float4*)p;
  float4 b = *(const float4*)(p + 4);
  split8v(a, b, hi, lo);
}

// ---------------- Phase 0: pre-split Wq|Wk|Wv into bf16 hi/lo ----------------
__global__ __launch_bounds__(256) void prep_kernel(
    const float* __restrict__ Wq, const float* __restrict__ Wk,
    const float* __restrict__ Wv,
    ushort_t* __restrict__ whi, ushort_t* __restrict__ wlo) {
  const int idx8 = (blockIdx.x * 256 + threadIdx.x) * 8;   // [0, 49152)
  const float* W = (idx8 < 16384) ? Wq : (idx8 < 32768) ? Wk : Wv;
  const int off = idx8 & 16383;
  short8 hi, lo;
  split8p(W + off, hi, lo);
  *(short8*)(whi + idx8) = hi;
  *(short8*)(wlo + idx8) = lo;
}

// ---------------- Phase 1: fused Q+K+V projection ----------------
// One block = 64 rows (4 waves x 16 rows, ONE A-fragment each). Per
// projection: DMA Wh -> LDS (32KB), sync, MFMA, sync, DMA Wl -> same LDS,
// sync, MFMA, sync, repack (16.9KB, reuses staging region) -> coalesced
// stores, sync. 782 blocks = 3.05/CU so block chains interleave.
__global__ __launch_bounds__(256) void qkv_fused_kernel(
    const float* __restrict__ h,
    const float* __restrict__ bq, const float* __restrict__ bk,
    const float* __restrict__ bv,
    const ushort_t* __restrict__ whi, const ushort_t* __restrict__ wlo,
    ushort_t* __restrict__ qs, ushort_t* __restrict__ ks, ushort_t* __restrict__ vs,
    int n) {
  __shared__ __align__(16) char lds_b[32768];    // B staging; repack reuses [0,16896)

  const int wave = threadIdx.x >> 6;
  const int l = threadIdx.x & 63;
  const int lm = l & 15;
  const int lq = l >> 4;
  const int m0 = blockIdx.x * 64 + wave * 16;

  // --- A: load 16 h rows, split to bf16 hi/lo ONCE; reused by all 3 projections.
  int ar = m0 + lm;  if (ar >= n) ar = n - 1;
  const float* ap = h + (size_t)ar * HID + lq * 8;
  short8 ah[4], al[4];
#pragma unroll
  for (int kt = 0; kt < 4; kt++) split8p(ap + kt * 32, ah[kt], al[kt]);

#pragma unroll 1
  for (int p = 0; p < 3; p++) {
    const ushort_t* __restrict__ Wh = whi + p * 16384;
    const ushort_t* __restrict__ Wl = wlo + p * 16384;
    const float* __restrict__ bias = (p == 0) ? bq : (p == 1) ? bk : bv;
    ushort_t* __restrict__ outp = (p == 0) ? qs : (p == 1) ? ks : vs;
    const int ostride = (p == 0) ? 256 : 128;   // q lives inside 512B fp32 out rows
    const float scale = (p == 0) ? 0.25f : 1.0f;

    f32x4 acc[8];
#pragma unroll
    for (int t = 0; t < 8; t++) acc[t] = (f32x4){0.f, 0.f, 0.f, 0.f};

    // ---- hi phase ----
#pragma unroll
    for (int jj = 0; jj < 8; jj++) {            // wave covers j = wave*8 + jj
      const int j = wave * 8 + jj, t = j >> 2, kt = j & 3;
      const ushort_t* gp = Wh + (t * 16 + lm) * HID + kt * 32 + lq * 8;
      __builtin_amdgcn_global_load_lds(
          (const __attribute__((address_space(1))) void*)gp,
          (__attribute__((address_space(3))) void*)(lds_b + j * 1024 + l * 16),
          16, 0, 0);
    }
    __syncthreads();                             // DMA drained for all waves
#pragma unroll
    for (int kt = 0; kt < 4; kt++) {
#pragma unroll
      for (int t = 0; t < 8; t++) {
        short8 bh = *(const short8*)(lds_b + (t * 4 + kt) * 1024 + l * 16);
        acc[t] = __builtin_amdgcn_mfma_f32_16x16x32_bf16(ah[kt], bh, acc[t], 0, 0, 0);
        acc[t] = __builtin_amdgcn_mfma_f32_16x16x32_bf16(al[kt], bh, acc[t], 0, 0, 0);
      }
    }
    __syncthreads();                             // all waves done reading hi

    // ---- lo phase (overwrites lds_b) ----
#pragma unroll
    for (int jj = 0; jj < 8; jj++) {
      const int j = wave * 8 + jj, t = j >> 2, kt = j & 3;
      const ushort_t* gp = Wl + (t * 16 + lm) * HID + kt * 32 + lq * 8;
      __builtin_amdgcn_global_load_lds(
          (const __attribute__((address_space(1))) void*)gp,
          (__attribute__((address_space(3))) void*)(lds_b + j * 1024 + l * 16),
          16, 0, 0);
    }
    __syncthreads();
#pragma unroll
    for (int kt = 0; kt < 4; kt++) {
#pragma unroll
      for (int t = 0; t < 8; t++) {
        short8 bl = *(const short8*)(lds_b + (t * 4 + kt) * 1024 + l * 16);
        acc[t] = __builtin_amdgcn_mfma_f32_16x16x32_bf16(ah[kt], bl, acc[t], 0, 0, 0);
      }
    }
    __syncthreads();                             // all waves done reading lo

    // ---- epilogue: fragments -> per-wave LDS repack -> coalesced stores ----
    // D[m][c]: c = lm + 16t, m = lq*4 + r (16 rows per wave).
    ushort_t* lo_ = (ushort_t*)lds_b + wave * 16 * OSTRIDE_LDS;
#pragma unroll
    for (int t = 0; t < 8; t++) {
      const int col = t * 16 + lm;
      const float bv_ = bias[col];
#pragma unroll
      for (int r = 0; r < 4; r++) {
        lo_[(lq * 4 + r) * OSTRIDE_LDS + col] = f2bf((acc[t][r] + bv_) * scale);
      }
    }
    asm volatile("s_waitcnt lgkmcnt(0)" ::: "memory");   // wave-local ordering
    __builtin_amdgcn_wave_barrier();

    const int rr = l >> 5;          // 0..1
    const int ch = l & 31;          // 8B chunk index
#pragma unroll
    for (int it = 0; it < 8; it++) {
      const int rw = it * 2 + rr;   // row within wave, 0..15
      const int grow = m0 + rw;
      short4v val = *(short4v*)(lo_ + rw * OSTRIDE_LDS + ch * 4);
      if (grow < n) *(short4v*)(outp + (size_t)grow * ostride + ch * 4) = val;
    }
    __syncthreads();   // repack reads done before next projection's DMA reuses LDS
  }
}

// ---------------- Phase 2: fused scores + softmax + aggregate ----------------
// One wave per row (r9 version verbatim — r10 trims regressed).
__global__ __launch_bounds__(256) void attn_kernel(
    const int* __restrict__ col_ind,
    const ushort_t* __restrict__ qs, const ushort_t* __restrict__ ks,
    const ushort_t* __restrict__ vs, float* __restrict__ out, int n) {
  __shared__ __align__(16) float lds_attn[4 * DEG * 8];  // [wave][edge][head]

  const int wv = threadIdx.x >> 6;
  const int l = threadIdx.x & 63;
  const int lm = l & 15;
  const int lq = l >> 4;

  int row = blockIdx.x * 4 + wv;
  if (row >= n) row = n - 1;
  const int eb = row * DEG;

  const int cm = col_ind[eb + lm];                 // this lane's A-operand edge
  const ushort_t* kp = ks + (size_t)cm * HID + lq * 8;
  const ushort_t* qp = qs + (size_t)row * 256;     // q embedded in out row

  short8 af[4];
  ushort_t qv[4];
#pragma unroll
  for (int kt = 0; kt < 4; kt++) {
    af[kt] = *(const short8*)(kp + kt * 32);
    qv[kt] = (lm < 8) ? qp[kt * 32 + lq * 8 + lm] : (ushort_t)0;
  }

  uint32 vreg[DEG];
#pragma unroll
  for (int e = 0; e < DEG; e++) {
    const int c = col_ind[eb + e];                 // wave-uniform -> s_load
    vreg[e] = *(const uint32*)(vs + (size_t)c * HID + 2 * l);
  }

  f32x4 acc = (f32x4){0.f, 0.f, 0.f, 0.f};
#pragma unroll
  for (int kt = 0; kt < 4; kt++) {
    short8 bf;
#pragma unroll
    for (int j = 0; j < 8; j++) bf[j] = (lm == j) ? (short)qv[kt] : (short)0;
    acc = __builtin_amdgcn_mfma_f32_16x16x32_bf16(af[kt], bf, acc, 0, 0, 0);
  }

  float m = fmaxf(fmaxf(acc[0], acc[1]), fmaxf(acc[2], acc[3]));
  m = fmaxf(m, __shfl_xor(m, 16, 64));
  m = fmaxf(m, __shfl_xor(m, 32, 64));
  float e0 = __expf(acc[0] - m), e1 = __expf(acc[1] - m);
  float e2 = __expf(acc[2] - m), e3 = __expf(acc[3] - m);
  float s = e0 + e1 + e2 + e3;
  s += __shfl_xor(s, 16, 64);
  s += __shfl_xor(s, 32, 64);
  const float inv = 1.0f / s;

  float* ap = &lds_attn[wv * (DEG * 8)];
  if (lm < 8) {
    ap[(lq * 4 + 0) * 8 + lm] = e0 * inv;
    ap[(lq * 4 + 1) * 8 + lm] = e1 * inv;
    ap[(lq * 4 + 2) * 8 + lm] = e2 * inv;
    ap[(lq * 4 + 3) * 8 + lm] = e3 * inv;
  }
  asm volatile("s_waitcnt lgkmcnt(0)" ::: "memory");
  __builtin_amdgcn_wave_barrier();

  const int h0 = 2 * (l & 3);
  float o0 = 0.f, o1 = 0.f;
#pragma unroll
  for (int e = 0; e < DEG; e++) {
    const float2 at = *(const float2*)(ap + e * 8 + h0);
    o0 += at.x * bf2f((ushort_t)(vreg[e] & 0xffffu));
    o1 += at.y * bf2f((ushort_t)(vreg[e] >> 16));
  }

  float2 o = {o0, o1};
  *(float2*)(out + (size_t)row * HID + 2 * l) = o;  // overwrites consumed q
}

extern "C" void kernel_launch(void* const* d_in, const int* in_sizes, int n_in,
                              void* d_out, int out_size, void* d_ws, size_t ws_size,
                              hipStream_t stream) {
  const float* h  = (const float*)d_in[0];
  const float* Wq = (const float*)d_in[1];
  const float* bq = (const float*)d_in[2];
  const float* Wk = (const float*)d_in[3];
  const float* bk = (const float*)d_in[4];
  const float* Wv = (const float*)d_in[5];
  const float* bv = (const float*)d_in[6];
  // d_in[7] = row_ptr (fixed degree 16) — unused
  const int* col_ind = (const int*)d_in[8];
  // d_in[9] = num_heads (= 8) — hardcoded in layout math

  const int n = in_sizes[0] / HID;  // 50000

  // ws layout (~25.8 MB): k, v bf16 tables + W hi/lo splits. q (bf16) lives in
  // the first 256 B of each row's 512 B fp32 out slot.
  ushort_t* ks  = (ushort_t*)d_ws;
  ushort_t* vs  = ks + (size_t)n * HID;
  ushort_t* whi = vs + (size_t)n * HID;
  ushort_t* wlo = whi + 3 * 16384;
  ushort_t* qs  = (ushort_t*)d_out;
  float* outf   = (float*)d_out;

  prep_kernel<<<24, 256, 0, stream>>>(Wq, Wk, Wv, whi, wlo);
  qkv_fused_kernel<<<(n + 63) / 64, 256, 0, stream>>>(h, bq, bk, bv, whi, wlo, qs, ks, vs, n);
  attn_kernel<<<(n + 3) / 4, 256, 0, stream>>>(col_ind, qs, ks, vs, outf, n);
}

// Round 12
// 173.296 us; speedup vs baseline: 1.0369x; 1.0369x over previous
//
#include <hip/hip_runtime.h>
#include <hip/hip_bf16.h>

// SparseMHA, fixed out-degree CSR graph attention. fp32 in/out.
// r11 -> r12: r11 (64-row tiles) regressed +5us: doubled grid doubled B-DMA
// traffic. Back to r9's 128-row tiles, but with BOTH Wh and Wl DMA'd into
// separate 32KB LDS buffers in ONE async burst (16 insts outstanding, ONE
// sync) -> DMA latency exposed once per projection, barriers 15 -> 9 per
// block. Repack uses the full 64KB (stride-132, conflict-free) after a sync.
// attn = r9 verbatim. Noise floor calibrated at ~3us (r11 attn = r9 attn
// measured +2.5us) — only structural changes from here.

typedef unsigned short ushort_t;
typedef unsigned int uint32;
typedef short short8 __attribute__((ext_vector_type(8)));
typedef short short4v __attribute__((ext_vector_type(4)));
typedef float f32x4 __attribute__((ext_vector_type(4)));

#define HID 128
#define DEG 16
#define OSTRIDE_LDS 132   // ushort row stride in LDS repack (bank-conflict-free)

__device__ __forceinline__ float bf2f(ushort_t u) {
  uint32 x = ((uint32)u) << 16;
  return __builtin_bit_cast(float, x);
}
__device__ __forceinline__ ushort_t f2bf(float f) {
  uint32 u = __builtin_bit_cast(uint32, f);
  u += 0x7fffu + ((u >> 16) & 1u);   // RNE
  return (ushort_t)(u >> 16);
}

// Packed split of 2 fp32 -> packed bf16 hi pair + lo pair (RNE, v_cvt_pk path).
__device__ __forceinline__ void split2(float x, float y, uint32& hi, uint32& lo) {
  __hip_bfloat162 h2 = __float22bfloat162_rn(float2{x, y});
  __builtin_memcpy(&hi, &h2, 4);
  float hx = __builtin_bit_cast(float, hi << 16);
  float hy = __builtin_bit_cast(float, hi & 0xffff0000u);
  __hip_bfloat162 l2 = __float22bfloat162_rn(float2{x - hx, y - hy});
  __builtin_memcpy(&lo, &l2, 4);
}

__device__ __forceinline__ void split8v(float4 a, float4 b, short8& hi, short8& lo) {
  uint32* hu = (uint32*)&hi;
  uint32* lu = (uint32*)&lo;
  split2(a.x, a.y, hu[0], lu[0]);
  split2(a.z, a.w, hu[1], lu[1]);
  split2(b.x, b.y, hu[2], lu[2]);
  split2(b.z, b.w, hu[3], lu[3]);
}

__device__ __forceinline__ void split8p(const float* __restrict__ p, short8& hi, short8& lo) {
  float4 a = *(const float4*)p;
  float4 b = *(const float4*)(p + 4);
  split8v(a, b, hi, lo);
}

// ---------------- Phase 0: pre-split Wq|Wk|Wv into bf16 hi/lo ----------------
__global__ __launch_bounds__(256) void prep_kernel(
    const float* __restrict__ Wq, const float* __restrict__ Wk,
    const float* __restrict__ Wv,
    ushort_t* __restrict__ whi, ushort_t* __restrict__ wlo) {
  const int idx8 = (blockIdx.x * 256 + threadIdx.x) * 8;   // [0, 49152)
  const float* W = (idx8 < 16384) ? Wq : (idx8 < 32768) ? Wk : Wv;
  const int off = idx8 & 16383;
  short8 hi, lo;
  split8p(W + off, hi, lo);
  *(short8*)(whi + idx8) = hi;
  *(short8*)(wlo + idx8) = lo;
}

// ---------------- Phase 1: fused Q+K+V projection ----------------
// One block = 128 rows (4 waves x 32 rows, 2 A-fragments each). Per
// projection: 16 DMAs (Wh->buf0, Wl->buf1) in one burst, ONE sync, all MFMAs
// from LDS, sync, repack (full 64KB region) + coalesced stores, sync.
__global__ __launch_bounds__(256) void qkv_fused_kernel(
    const float* __restrict__ h,
    const float* __restrict__ bq, const float* __restrict__ bk,
    const float* __restrict__ bv,
    const ushort_t* __restrict__ whi, const ushort_t* __restrict__ wlo,
    ushort_t* __restrict__ qs, ushort_t* __restrict__ ks, ushort_t* __restrict__ vs,
    int n) {
  __shared__ __align__(16) char lds_raw[65536];  // buf0 [0,32K) Wh | buf1 [32K,64K) Wl
  char* buf0 = lds_raw;
  char* buf1 = lds_raw + 32768;

  const int wave = threadIdx.x >> 6;
  const int l = threadIdx.x & 63;
  const int lm = l & 15;
  const int lq = l >> 4;
  const int m0 = blockIdx.x * 128 + wave * 32;

  // --- A: load h rows and split to bf16 hi/lo ONCE; reused by all 3 projections.
  int ar0 = m0 + lm;        if (ar0 >= n) ar0 = n - 1;
  int ar1 = m0 + 16 + lm;   if (ar1 >= n) ar1 = n - 1;
  const float* ap0 = h + (size_t)ar0 * HID + lq * 8;
  const float* ap1 = h + (size_t)ar1 * HID + lq * 8;
  short8 ah0[4], al0[4], ah1[4], al1[4];
#pragma unroll
  for (int kt = 0; kt < 4; kt++) {
    split8p(ap0 + kt * 32, ah0[kt], al0[kt]);
    split8p(ap1 + kt * 32, ah1[kt], al1[kt]);
  }

#pragma unroll 1
  for (int p = 0; p < 3; p++) {
    const ushort_t* __restrict__ Wh = whi + p * 16384;
    const ushort_t* __restrict__ Wl = wlo + p * 16384;
    const float* __restrict__ bias = (p == 0) ? bq : (p == 1) ? bk : bv;
    ushort_t* __restrict__ outp = (p == 0) ? qs : (p == 1) ? ks : vs;
    const int ostride = (p == 0) ? 256 : 128;   // q lives inside 512B fp32 out rows
    const float scale = (p == 0) ? 0.25f : 1.0f;

    // ---- one DMA burst: Wh -> buf0 AND Wl -> buf1 (16 insts outstanding) ----
#pragma unroll
    for (int jj = 0; jj < 8; jj++) {            // wave covers j = wave*8 + jj
      const int j = wave * 8 + jj, t = j >> 2, kt = j & 3;
      const int goff = (t * 16 + lm) * HID + kt * 32 + lq * 8;
      __builtin_amdgcn_global_load_lds(
          (const __attribute__((address_space(1))) void*)(Wh + goff),
          (__attribute__((address_space(3))) void*)(buf0 + j * 1024 + l * 16),
          16, 0, 0);
      __builtin_amdgcn_global_load_lds(
          (const __attribute__((address_space(1))) void*)(Wl + goff),
          (__attribute__((address_space(3))) void*)(buf1 + j * 1024 + l * 16),
          16, 0, 0);
    }
    __syncthreads();                             // single DMA drain per projection

    f32x4 acc[2][8];
#pragma unroll
    for (int f = 0; f < 2; f++)
#pragma unroll
      for (int t = 0; t < 8; t++) acc[f][t] = (f32x4){0.f, 0.f, 0.f, 0.f};

#pragma unroll
    for (int kt = 0; kt < 4; kt++) {
#pragma unroll
      for (int t = 0; t < 8; t++) {
        const int so = (t * 4 + kt) * 1024 + l * 16;
        short8 bh = *(const short8*)(buf0 + so);
        short8 bl = *(const short8*)(buf1 + so);
        acc[0][t] = __builtin_amdgcn_mfma_f32_16x16x32_bf16(ah0[kt], bh, acc[0][t], 0, 0, 0);
        acc[0][t] = __builtin_amdgcn_mfma_f32_16x16x32_bf16(al0[kt], bh, acc[0][t], 0, 0, 0);
        acc[0][t] = __builtin_amdgcn_mfma_f32_16x16x32_bf16(ah0[kt], bl, acc[0][t], 0, 0, 0);
        acc[1][t] = __builtin_amdgcn_mfma_f32_16x16x32_bf16(ah1[kt], bh, acc[1][t], 0, 0, 0);
        acc[1][t] = __builtin_amdgcn_mfma_f32_16x16x32_bf16(al1[kt], bh, acc[1][t], 0, 0, 0);
        acc[1][t] = __builtin_amdgcn_mfma_f32_16x16x32_bf16(ah1[kt], bl, acc[1][t], 0, 0, 0);
      }
    }
    __syncthreads();                             // all waves done reading buf0/buf1

    // ---- epilogue: fragments -> LDS repack (full 64KB region) -> stores ----
    // D[m][c]: c = lm + 16t, m = f*16 + lq*4 + r.
    ushort_t* lo_ = (ushort_t*)lds_raw + wave * 32 * OSTRIDE_LDS;
#pragma unroll
    for (int t = 0; t < 8; t++) {
      const int col = t * 16 + lm;
      const float bv_ = bias[col];
#pragma unroll
      for (int f = 0; f < 2; f++) {
#pragma unroll
        for (int r = 0; r < 4; r++) {
          lo_[(f * 16 + lq * 4 + r) * OSTRIDE_LDS + col] = f2bf((acc[f][t][r] + bv_) * scale);
        }
      }
    }
    asm volatile("s_waitcnt lgkmcnt(0)" ::: "memory");   // wave-local ordering
    __builtin_amdgcn_wave_barrier();

    const int rr = l >> 5;          // 0..1
    const int ch = l & 31;          // 8B chunk index
#pragma unroll
    for (int it = 0; it < 16; it++) {
      const int rw = it * 2 + rr;   // row within wave, 0..31
      const int grow = m0 + rw;
      short4v val = *(short4v*)(lo_ + rw * OSTRIDE_LDS + ch * 4);
      if (grow < n) *(short4v*)(outp + (size_t)grow * ostride + ch * 4) = val;
    }
    __syncthreads();   // repack reads done before next projection's DMA reuses LDS
  }
}

// ---------------- Phase 2: fused scores + softmax + aggregate ----------------
// One wave per row (r9 verbatim).
__global__ __launch_bounds__(256) void attn_kernel(
    const int* __restrict__ col_ind,
    const ushort_t* __restrict__ qs, const ushort_t* __restrict__ ks,
    const ushort_t* __restrict__ vs, float* __restrict__ out, int n) {
  __shared__ __align__(16) float lds_attn[4 * DEG * 8];  // [wave][edge][head]

  const int wv = threadIdx.x >> 6;
  const int l = threadIdx.x & 63;
  const int lm = l & 15;
  const int lq = l >> 4;

  int row = blockIdx.x * 4 + wv;
  if (row >= n) row = n - 1;
  const int eb = row * DEG;

  const int cm = col_ind[eb + lm];                 // this lane's A-operand edge
  const ushort_t* kp = ks + (size_t)cm * HID + lq * 8;
  const ushort_t* qp = qs + (size_t)row * 256;     // q embedded in out row

  short8 af[4];
  ushort_t qv[4];
#pragma unroll
  for (int kt = 0; kt < 4; kt++) {
    af[kt] = *(const short8*)(kp + kt * 32);
    qv[kt] = (lm < 8) ? qp[kt * 32 + lq * 8 + lm] : (ushort_t)0;
  }

  uint32 vreg[DEG];
#pragma unroll
  for (int e = 0; e < DEG; e++) {
    const int c = col_ind[eb + e];                 // wave-uniform -> s_load
    vreg[e] = *(const uint32*)(vs + (size_t)c * HID + 2 * l);
  }

  f32x4 acc = (f32x4){0.f, 0.f, 0.f, 0.f};
#pragma unroll
  for (int kt = 0; kt < 4; kt++) {
    short8 bf;
#pragma unroll
    for (int j = 0; j < 8; j++) bf[j] = (lm == j) ? (short)qv[kt] : (short)0;
    acc = __builtin_amdgcn_mfma_f32_16x16x32_bf16(af[kt], bf, acc, 0, 0, 0);
  }

  float m = fmaxf(fmaxf(acc[0], acc[1]), fmaxf(acc[2], acc[3]));
  m = fmaxf(m, __shfl_xor(m, 16, 64));
  m = fmaxf(m, __shfl_xor(m, 32, 64));
  float e0 = __expf(acc[0] - m), e1 = __expf(acc[1] - m);
  float e2 = __expf(acc[2] - m), e3 = __expf(acc[3] - m);
  float s = e0 + e1 + e2 + e3;
  s += __shfl_xor(s, 16, 64);
  s += __shfl_xor(s, 32, 64);
  const float inv = 1.0f / s;

  float* ap = &lds_attn[wv * (DEG * 8)];
  if (lm < 8) {
    ap[(lq * 4 + 0) * 8 + lm] = e0 * inv;
    ap[(lq * 4 + 1) * 8 + lm] = e1 * inv;
    ap[(lq * 4 + 2) * 8 + lm] = e2 * inv;
    ap[(lq * 4 + 3) * 8 + lm] = e3 * inv;
  }
  asm volatile("s_waitcnt lgkmcnt(0)" ::: "memory");
  __builtin_amdgcn_wave_barrier();

  const int h0 = 2 * (l & 3);
  float o0 = 0.f, o1 = 0.f;
#pragma unroll
  for (int e = 0; e < DEG; e++) {
    const float2 at = *(const float2*)(ap + e * 8 + h0);
    o0 += at.x * bf2f((ushort_t)(vreg[e] & 0xffffu));
    o1 += at.y * bf2f((ushort_t)(vreg[e] >> 16));
  }

  float2 o = {o0, o1};
  *(float2*)(out + (size_t)row * HID + 2 * l) = o;  // overwrites consumed q
}

extern "C" void kernel_launch(void* const* d_in, const int* in_sizes, int n_in,
                              void* d_out, int out_size, void* d_ws, size_t ws_size,
                              hipStream_t stream) {
  const float* h  = (const float*)d_in[0];
  const float* Wq = (const float*)d_in[1];
  const float* bq = (const float*)d_in[2];
  const float* Wk = (const float*)d_in[3];
  const float* bk = (const float*)d_in[4];
  const float* Wv = (const float*)d_in[5];
  const float* bv = (const float*)d_in[6];
  // d_in[7] = row_ptr (fixed degree 16) — unused
  const int* col_ind = (const int*)d_in[8];
  // d_in[9] = num_heads (= 8) — hardcoded in layout math

  const int n = in_sizes[0] / HID;  // 50000

  // ws layout (~25.8 MB): k, v bf16 tables + W hi/lo splits. q (bf16) lives in
  // the first 256 B of each row's 512 B fp32 out slot.
  ushort_t* ks  = (ushort_t*)d_ws;
  ushort_t* vs  = ks + (size_t)n * HID;
  ushort_t* whi = vs + (size_t)n * HID;
  ushort_t* wlo = whi + 3 * 16384;
  ushort_t* qs  = (ushort_t*)d_out;
  float* outf   = (float*)d_out;

  prep_kernel<<<24, 256, 0, stream>>>(Wq, Wk, Wv, whi, wlo);
  qkv_fused_kernel<<<(n + 127) / 128, 256, 0, stream>>>(h, bq, bk, bv, whi, wlo, qs, ks, vs, n);
  attn_kernel<<<(n + 3) / 4, 256, 0, stream>>>(col_ind, qs, ks, vs, outf, n);
}